// Round 1
// baseline (257.300 us; speedup 1.0000x reference)
//
#include <hip/hip_runtime.h>
#include <hip/hip_bf16.h>
#include <math.h>

#define DEV static __device__ __forceinline__

typedef float f32x4 __attribute__((ext_vector_type(4)));
typedef short s16x8 __attribute__((ext_vector_type(8)));
typedef unsigned short u16;
typedef unsigned int u32;

// problem constants
#define ROWS 16384                    // 2*B*N
#define SSCALE 0.35355339059327379f   // 64^-0.25

DEV f32x4 mfma16(s16x8 a, s16x8 b, f32x4 c) {
  return __builtin_amdgcn_mfma_f32_16x16x32_bf16(a, b, c, 0, 0, 0);
}

DEV float bf2f(u16 x) { u32 u = ((u32)x) << 16; float f; __builtin_memcpy(&f, &u, 4); return f; }
DEV u16 f2bf(float x) { __hip_bfloat16 b = __float2bfloat16(x); u16 r; __builtin_memcpy(&r, &b, 2); return r; }

DEV void gload_lds16(const void* g, void* l) {
  __builtin_amdgcn_global_load_lds((const __attribute__((address_space(1))) u32*)g,
                                   (__attribute__((address_space(3))) u32*)l, 16, 0, 0);
}

// ---------------------------------------------------------------------------
// prep: transpose+convert weights to bf16 [out][in], convert x0|x1 -> Xb bf16
// ---------------------------------------------------------------------------
__global__ __launch_bounds__(256) void k_prep(
    const float* __restrict__ x0, const float* __restrict__ x1,
    const float* __restrict__ Wqk, const float* __restrict__ Wv,
    const float* __restrict__ Wo, const float* __restrict__ W1,
    const float* __restrict__ W2,
    u16* __restrict__ bt_qkv, u16* __restrict__ bt_o,
    u16* __restrict__ bt_1, u16* __restrict__ bt_2, u16* __restrict__ Xb)
{
  int tid = blockIdx.x * 256 + threadIdx.x;
  if (tid < 131072) {                        // bt_qkv [512][256]
    int c = tid >> 8, k = tid & 255;
    float v = (c < 256) ? Wqk[k * 256 + c] : Wv[k * 256 + (c - 256)];
    bt_qkv[tid] = f2bf(v);
  } else if (tid < 131072 + 65536) {         // bt_o [256][256]
    int t = tid - 131072; int c = t >> 8, k = t & 255;
    bt_o[t] = f2bf(Wo[k * 256 + c]);
  } else if (tid < 131072 + 65536 + 262144) {  // bt_1 [512][512]
    int t = tid - (131072 + 65536); int c = t >> 9, k = t & 511;
    bt_1[t] = f2bf(W1[k * 512 + c]);
  } else if (tid < 589824) {                 // bt_2 [256][512]
    int t = tid - (131072 + 65536 + 262144); int c = t >> 9, k = t & 511;
    bt_2[t] = f2bf(W2[k * 256 + c]);
  } else {                                   // Xb [16384][256]
    int t = tid - 589824;
    float v = (t < 8192 * 256) ? x0[t] : x1[t - 8192 * 256];
    Xb[t] = f2bf(v);
  }
}

// ---------------------------------------------------------------------------
// GEMM: C[16384 x Ncols] = A(bf16,[M][KD], optionally split A1|A2 at K1) @ Bt^T
// Bt is [Ncols][KD] bf16 (pre-transposed weights). 128x128 tile, 4 waves,
// BK=32, double-buffered global_load_lds, XOR-swizzled LDS (conflict-free).
// EPI 0: qk/vt scatter (+bias, *SS / +bias)   EPI 1: bf16 out (+bias)
// EPI 3: f32 out (+bias +residual x)
// ---------------------------------------------------------------------------
template <int KD, int K1, int EPI>
__global__ __launch_bounds__(256, 2) void k_gemm(
    const u16* __restrict__ A1, const u16* __restrict__ A2,
    const u16* __restrict__ Bt,
    const float* __restrict__ bias, const float* __restrict__ bias2,
    const float* __restrict__ res0, const float* __restrict__ res1,
    u16* __restrict__ outb, u16* __restrict__ outb2,
    float* __restrict__ outf, int Ncols)
{
  __shared__ char lds[32768];
  char* ldsA = lds;
  char* ldsB = lds + 16384;
  const int tid = threadIdx.x;
  const int lane = tid & 63;
  const int w = tid >> 6;
  const int wm = w >> 1, wn = w & 1;
  const int g = lane >> 4, li = lane & 15;
  const int m0 = blockIdx.x * 128, n0 = blockIdx.y * 128;

  auto stage = [&](int buf, int t) {
    const int k0 = t * 32;
#pragma unroll
    for (int it = 0; it < 2; ++it) {
      int chunk = it * 256 + w * 64 + lane;
      int row = chunk >> 2, c = chunk & 3;
      int kc = k0 + ((c ^ ((row >> 1) & 3)) << 3);
      const u16* src = (kc < K1) ? (A1 + (size_t)(m0 + row) * K1 + kc)
                                 : (A2 + (size_t)(m0 + row) * (KD - K1) + (kc - K1));
      gload_lds16(src, ldsA + buf * 8192 + (it * 256 + w * 64) * 16);
    }
#pragma unroll
    for (int it = 0; it < 2; ++it) {
      int chunk = it * 256 + w * 64 + lane;
      int row = chunk >> 2, c = chunk & 3;
      int kc = k0 + ((c ^ ((row >> 1) & 3)) << 3);
      gload_lds16(Bt + (size_t)(n0 + row) * KD + kc,
                  ldsB + buf * 8192 + (it * 256 + w * 64) * 16);
    }
  };

  f32x4 acc[4][4] = {};

  stage(0, 0);
  __syncthreads();
  const int NT = KD / 32;
  for (int t = 0; t < NT; ++t) {
    if (t + 1 < NT) stage((t + 1) & 1, t + 1);
    const char* bufA = ldsA + (t & 1) * 8192;
    const char* bufB = ldsB + (t & 1) * 8192;
    s16x8 af[4], bfr[4];
#pragma unroll
    for (int rt = 0; rt < 4; ++rt) {
      int row = wm * 64 + rt * 16 + li;
      af[rt] = *(const s16x8*)(bufA + row * 64 + ((g ^ ((row >> 1) & 3)) << 4));
    }
#pragma unroll
    for (int ct = 0; ct < 4; ++ct) {
      int col = wn * 64 + ct * 16 + li;
      bfr[ct] = *(const s16x8*)(bufB + col * 64 + ((g ^ ((col >> 1) & 3)) << 4));
    }
#pragma unroll
    for (int rt = 0; rt < 4; ++rt)
#pragma unroll
      for (int ct = 0; ct < 4; ++ct)
        acc[rt][ct] = mfma16(af[rt], bfr[ct], acc[rt][ct]);
    __syncthreads();
  }

#pragma unroll
  for (int rt = 0; rt < 4; ++rt) {
#pragma unroll
    for (int ct = 0; ct < 4; ++ct) {
#pragma unroll
      for (int r = 0; r < 4; ++r) {
        int grow = m0 + wm * 64 + rt * 16 + g * 4 + r;
        int gcol = n0 + wn * 64 + ct * 16 + li;
        float v = acc[rt][ct][r];
        if (EPI == 0) {
          int dir = grow >> 13, b = (grow >> 11) & 3, n = grow & 2047;
          if (gcol < 256) {
            int h = gcol >> 6, dh = gcol & 63;
            float q = (v + bias[gcol]) * SSCALE;
            outb[((size_t)(dir * 16 + b * 4 + h) * 2048 + n) * 64 + dh] = f2bf(q);
          } else {
            int c2 = gcol - 256; int h = c2 >> 6, dh = c2 & 63;
            outb2[((size_t)(dir * 16 + b * 4 + h) * 64 + dh) * 2048 + n] = f2bf(v + bias2[c2]);
          }
        } else if (EPI == 1) {
          outb[(size_t)grow * Ncols + gcol] = f2bf(v + bias[gcol]);
        } else {
          float x = (grow < 8192) ? res0[(size_t)grow * 256 + gcol]
                                  : res1[(size_t)(grow - 8192) * 256 + gcol];
          outf[(size_t)grow * 256 + gcol] = v + bias[gcol] + x;
        }
      }
    }
  }
}

// ---------------------------------------------------------------------------
// attention: 32 problems (dir,b,h) x 16 q-tiles of 128. 4 waves, 32 q-rows/wave.
// Logits are tiny (|s|<~1) -> softmax without max subtraction is safe:
// O = (sum_j exp(s_j) v_j) / (sum_j exp(s_j)), single pass, no rescale.
// ---------------------------------------------------------------------------
__global__ __launch_bounds__(256, 2) void k_attn(
    const u16* __restrict__ qk, const u16* __restrict__ vt, u16* __restrict__ m_all)
{
  __shared__ char Kl[2][8192];
  __shared__ char Vl[2][8192];
  __shared__ char Pl[4][4096];
  const int tid = threadIdx.x, lane = tid & 63, w = tid >> 6;
  const int g = lane >> 4, li = lane & 15;
  const int qblk = blockIdx.x & 15;
  const int p = blockIdx.x >> 4;
  const int dir = p & 1;
  const int bh = p >> 1;  // b*4 + h
  const char* Qg = (const char*)qk + ((size_t)(dir * 16 + bh)) * 2048 * 64 * 2;
  const char* Kg = (const char*)qk + ((size_t)((dir ^ 1) * 16 + bh)) * 2048 * 64 * 2;
  const char* Vg = (const char*)vt + ((size_t)((dir ^ 1) * 16 + bh)) * 64 * 2048 * 2;
  const int q0 = qblk * 128 + w * 32;

  // Q fragments in registers (reused across the whole j loop)
  s16x8 qf[2][2];
#pragma unroll
  for (int qt = 0; qt < 2; ++qt)
#pragma unroll
    for (int ks = 0; ks < 2; ++ks)
      qf[qt][ks] = *(const s16x8*)(Qg + (size_t)(q0 + qt * 16 + li) * 128 + ks * 64 + g * 16);

  auto stageKV = [&](int buf, int jt) {
#pragma unroll
    for (int it = 0; it < 2; ++it) {
      int chunk = it * 256 + w * 64 + lane;
      int row = chunk >> 3, c = chunk & 7;
      int cc = (c ^ (row & 7)) << 4;
      gload_lds16(Kg + (size_t)(jt * 64 + row) * 128 + cc, &Kl[buf][(it * 256 + w * 64) * 16]);
    }
#pragma unroll
    for (int it = 0; it < 2; ++it) {
      int chunk = it * 256 + w * 64 + lane;
      int row = chunk >> 3, c = chunk & 7;
      int cc = (c ^ (row & 7)) << 4;
      gload_lds16(Vg + (size_t)row * 4096 + jt * 128 + cc, &Vl[buf][(it * 256 + w * 64) * 16]);
    }
  };

  f32x4 acco[2][4] = {};
  float accl[2][4] = {};

  stageKV(0, 0);
  __syncthreads();
  for (int jt = 0; jt < 32; ++jt) {
    if (jt + 1 < 32) stageKV((jt + 1) & 1, jt + 1);
    const char* Kb = Kl[jt & 1];
    const char* Vb = Vl[jt & 1];

    // V fragments for this tile
    s16x8 vf[4][2];
#pragma unroll
    for (int dt = 0; dt < 4; ++dt)
#pragma unroll
      for (int ks = 0; ks < 2; ++ks) {
        int row = dt * 16 + li;
        vf[dt][ks] = *(const s16x8*)(Vb + row * 128 + (((ks * 4 + g) ^ (row & 7)) << 4));
      }

    // S = Q K^T, P = exp(S), accumulate row sums, stash P (bf16) in LDS
#pragma unroll
    for (int qt = 0; qt < 2; ++qt) {
#pragma unroll
      for (int kt = 0; kt < 4; ++kt) {
        f32x4 s = {0.f, 0.f, 0.f, 0.f};
#pragma unroll
        for (int ks = 0; ks < 2; ++ks) {
          int row = kt * 16 + li;
          s16x8 kf = *(const s16x8*)(Kb + row * 128 + (((ks * 4 + g) ^ (row & 7)) << 4));
          s = mfma16(qf[qt][ks], kf, s);
        }
#pragma unroll
        for (int r = 0; r < 4; ++r) {
          float pv = __expf(s[r]);
          accl[qt][r] += pv;
          int q = qt * 16 + g * 4 + r;
          int key = kt * 16 + li;
          *(u16*)(&Pl[w][q * 128 + ((key * 2) ^ ((q & 7) << 4))]) = f2bf(pv);
        }
      }
    }

    // O += P V  (compiler inserts lgkmcnt between same-wave ds_write/ds_read)
#pragma unroll
    for (int qt = 0; qt < 2; ++qt) {
      s16x8 pf[2];
#pragma unroll
      for (int ks = 0; ks < 2; ++ks) {
        int qrow = qt * 16 + li;
        pf[ks] = *(const s16x8*)(&Pl[w][qrow * 128 + (((ks * 4 + g) << 4) ^ ((qrow & 7) << 4))]);
      }
#pragma unroll
      for (int dt = 0; dt < 4; ++dt)
#pragma unroll
        for (int ks = 0; ks < 2; ++ks)
          acco[qt][dt] = mfma16(pf[ks], vf[dt][ks], acco[qt][dt]);
    }
    __syncthreads();
  }

  // finish row sums across the 16 column-lanes of each group
  float inv[2][4];
#pragma unroll
  for (int qt = 0; qt < 2; ++qt)
#pragma unroll
    for (int r = 0; r < 4; ++r) {
      float v = accl[qt][r];
      v += __shfl_xor(v, 1); v += __shfl_xor(v, 2);
      v += __shfl_xor(v, 4); v += __shfl_xor(v, 8);
      inv[qt][r] = 1.0f / v;
    }

  const int b = bh >> 2, h = bh & 3;
  const size_t rowbase = (size_t)dir * 8192 + (size_t)b * 2048 + q0;
#pragma unroll
  for (int qt = 0; qt < 2; ++qt)
#pragma unroll
    for (int dt = 0; dt < 4; ++dt)
#pragma unroll
      for (int r = 0; r < 4; ++r) {
        int q = qt * 16 + g * 4 + r;
        int dh = dt * 16 + li;
        m_all[(rowbase + q) * 256 + h * 64 + dh] = f2bf(acco[qt][dt][r] * inv[qt][r]);
      }
}

// ---------------------------------------------------------------------------
// layernorm (over 512) + exact gelu; one wave per row
// ---------------------------------------------------------------------------
__global__ __launch_bounds__(256) void k_ln_gelu(
    const u16* __restrict__ h, const float* __restrict__ lg,
    const float* __restrict__ lb, u16* __restrict__ o)
{
  int lane = threadIdx.x & 63;
  size_t row = blockIdx.x * 4 + (threadIdx.x >> 6);
  s16x8 v = *(const s16x8*)(h + row * 512 + lane * 8);
  float f[8], s = 0.f, s2 = 0.f;
#pragma unroll
  for (int j = 0; j < 8; ++j) { f[j] = bf2f((u16)v[j]); s += f[j]; s2 += f[j] * f[j]; }
#pragma unroll
  for (int m = 1; m < 64; m <<= 1) { s += __shfl_xor(s, m); s2 += __shfl_xor(s2, m); }
  float mu = s * (1.0f / 512.0f);
  float var = s2 * (1.0f / 512.0f) - mu * mu;
  float rs = rsqrtf(var + 1e-5f);
  s16x8 ov;
#pragma unroll
  for (int j = 0; j < 8; ++j) {
    int c = lane * 8 + j;
    float y = (f[j] - mu) * rs * lg[c] + lb[c];
    float ge = 0.5f * y * (1.0f + erff(y * 0.70710678118654752f));
    ov[j] = (short)f2bf(ge);
  }
  *(s16x8*)(o + row * 512 + lane * 8) = ov;
}

// ---------------------------------------------------------------------------
extern "C" void kernel_launch(void* const* d_in, const int* in_sizes, int n_in,
                              void* d_out, int out_size, void* d_ws, size_t ws_size,
                              hipStream_t stream)
{
  const float* x0  = (const float*)d_in[0];
  const float* x1  = (const float*)d_in[1];
  const float* Wqk = (const float*)d_in[2];
  const float* bqk = (const float*)d_in[3];
  const float* Wv  = (const float*)d_in[4];
  const float* bv  = (const float*)d_in[5];
  const float* Wo  = (const float*)d_in[6];
  const float* bo  = (const float*)d_in[7];
  const float* W1  = (const float*)d_in[8];
  const float* b1  = (const float*)d_in[9];
  const float* lg  = (const float*)d_in[10];
  const float* lb  = (const float*)d_in[11];
  const float* W2  = (const float*)d_in[12];
  const float* b2  = (const float*)d_in[13];
  float* out = (float*)d_out;
  char* ws = (char*)d_ws;

  u16* Xb    = (u16*)(ws + 0);          // 16384x256 bf16
  u16* qk    = (u16*)(ws + 8388608);    // [2][4][4][2048][64] bf16 (scaled)
  u16* vt    = (u16*)(ws + 16777216);   // [2][4][4][64][2048] bf16 (V transposed)
  u16* m_all = (u16*)(ws + 25165824);   // 16384x256 bf16
  u16* mo    = (u16*)(ws + 33554432);   // 16384x256 bf16
  u16* hpre  = (u16*)(ws + 41943040);   // 16384x512 bf16
  u16* gact  = (u16*)(ws + 58720256);   // 16384x512 bf16
  u16* btqkv = (u16*)(ws + 75497472);   // [512][256]
  u16* bto   = (u16*)(ws + 75759616);   // [256][256]
  u16* bt1   = (u16*)(ws + 75890688);   // [512][512]
  u16* bt2   = (u16*)(ws + 76414976);   // [256][512]

  k_prep<<<dim3(18688), dim3(256), 0, stream>>>(x0, x1, Wqk, Wv, Wo, W1, W2,
                                                btqkv, bto, bt1, bt2, Xb);
  k_gemm<256, 256, 0><<<dim3(128, 4), dim3(256), 0, stream>>>(
      Xb, nullptr, btqkv, bqk, bv, nullptr, nullptr, qk, vt, nullptr, 512);
  k_attn<<<dim3(512), dim3(256), 0, stream>>>(qk, vt, m_all);
  k_gemm<256, 256, 1><<<dim3(128, 2), dim3(256), 0, stream>>>(
      m_all, nullptr, bto, bo, nullptr, nullptr, nullptr, mo, nullptr, nullptr, 256);
  k_gemm<512, 256, 1><<<dim3(128, 4), dim3(256), 0, stream>>>(
      Xb, mo, bt1, b1, nullptr, nullptr, nullptr, hpre, nullptr, nullptr, 512);
  k_ln_gelu<<<dim3(4096), dim3(256), 0, stream>>>(hpre, lg, lb, gact);
  k_gemm<512, 512, 3><<<dim3(128, 2), dim3(256), 0, stream>>>(
      gact, nullptr, bt2, b2, nullptr, x0, x1, nullptr, nullptr, out, 256);
}

// Round 2
// 235.676 us; speedup vs baseline: 1.0918x; 1.0918x over previous
//
#include <hip/hip_runtime.h>
#include <hip/hip_bf16.h>
#include <math.h>

#define DEV static __device__ __forceinline__

typedef float f32x4 __attribute__((ext_vector_type(4)));
typedef short s16x8 __attribute__((ext_vector_type(8)));
typedef unsigned short u16;
typedef unsigned int u32;
typedef u32 u32x2 __attribute__((ext_vector_type(2)));
typedef u16 u16x4 __attribute__((ext_vector_type(4)));

// problem constants
#define ROWS 16384                    // 2*B*N
#define SSCALE 0.35355339059327379f   // 64^-0.25

DEV f32x4 mfma16(s16x8 a, s16x8 b, f32x4 c) {
  return __builtin_amdgcn_mfma_f32_16x16x32_bf16(a, b, c, 0, 0, 0);
}

DEV float bf2f(u16 x) { u32 u = ((u32)x) << 16; float f; __builtin_memcpy(&f, &u, 4); return f; }
DEV u16 f2bf(float x) { __hip_bfloat16 b = __float2bfloat16(x); u16 r; __builtin_memcpy(&r, &b, 2); return r; }

DEV void gload_lds16(const void* g, void* l) {
  __builtin_amdgcn_global_load_lds((const __attribute__((address_space(1))) u32*)g,
                                   (__attribute__((address_space(3))) u32*)l, 16, 0, 0);
}

// ---------------------------------------------------------------------------
// prep: transpose+convert weights to bf16 [out][in], convert x0|x1 -> Xb bf16
// ---------------------------------------------------------------------------
__global__ __launch_bounds__(256) void k_prep(
    const float* __restrict__ x0, const float* __restrict__ x1,
    const float* __restrict__ Wqk, const float* __restrict__ Wv,
    const float* __restrict__ Wo, const float* __restrict__ W1,
    const float* __restrict__ W2,
    u16* __restrict__ bt_qkv, u16* __restrict__ bt_o,
    u16* __restrict__ bt_1, u16* __restrict__ bt_2, u16* __restrict__ Xb)
{
  int tid = blockIdx.x * 256 + threadIdx.x;
  if (tid < 131072) {                        // bt_qkv [512][256]
    int c = tid >> 8, k = tid & 255;
    float v = (c < 256) ? Wqk[k * 256 + c] : Wv[k * 256 + (c - 256)];
    bt_qkv[tid] = f2bf(v);
  } else if (tid < 131072 + 65536) {         // bt_o [256][256]
    int t = tid - 131072; int c = t >> 8, k = t & 255;
    bt_o[t] = f2bf(Wo[k * 256 + c]);
  } else if (tid < 131072 + 65536 + 262144) {  // bt_1 [512][512]
    int t = tid - (131072 + 65536); int c = t >> 9, k = t & 511;
    bt_1[t] = f2bf(W1[k * 512 + c]);
  } else if (tid < 589824) {                 // bt_2 [256][512]
    int t = tid - (131072 + 65536 + 262144); int c = t >> 9, k = t & 511;
    bt_2[t] = f2bf(W2[k * 256 + c]);
  } else {                                   // Xb [16384][256]
    int t = tid - 589824;
    float v = (t < 8192 * 256) ? x0[t] : x1[t - 8192 * 256];
    Xb[t] = f2bf(v);
  }
}

// ---------------------------------------------------------------------------
// GEMM: C[16384 x Ncols] = A(bf16,[M][KD], optionally split A1|A2 at K1) @ Bt^T
// Bt is [Ncols][KD] bf16. 128xBN tile, 4 waves, BK=32, double-buffered
// global_load_lds, XOR-swizzled LDS. BN=64 variant doubles the grid for
// N=256 outputs (grid 256 -> 512 blocks => 2 blocks/CU).
// EPI 0: qk/vt scatter (+bias, *SS / +bias, packed-n stores)
// EPI 1: bf16 out (+bias)      EPI 3: f32 out (+bias +residual x)
// ---------------------------------------------------------------------------
template <int KD, int K1, int EPI, int BN>
__global__ __launch_bounds__(256, 2) void k_gemm(
    const u16* __restrict__ A1, const u16* __restrict__ A2,
    const u16* __restrict__ Bt,
    const float* __restrict__ bias, const float* __restrict__ bias2,
    const float* __restrict__ res0, const float* __restrict__ res1,
    u16* __restrict__ outb, u16* __restrict__ outb2,
    float* __restrict__ outf, int Ncols)
{
  constexpr int MR = (BN == 128) ? 4 : 2;       // row-tiles per wave
  __shared__ char lds[16384 + 2 * BN * 64];
  char* ldsA = lds;
  char* ldsB = lds + 16384;
  const int tid = threadIdx.x;
  const int lane = tid & 63;
  const int w = tid >> 6;
  const int wm = (BN == 128) ? (w >> 1) : w;
  const int wn = (BN == 128) ? (w & 1) : 0;
  const int g = lane >> 4, li = lane & 15;
  const int m0 = blockIdx.x * 128, n0 = blockIdx.y * BN;

  auto stage = [&](int buf, int t) {
    const int k0 = t * 32;
#pragma unroll
    for (int it = 0; it < 2; ++it) {
      int chunk = it * 256 + w * 64 + lane;
      int row = chunk >> 2, c = chunk & 3;
      int kc = k0 + ((c ^ ((row >> 1) & 3)) << 3);
      const u16* src = (kc < K1) ? (A1 + (size_t)(m0 + row) * K1 + kc)
                                 : (A2 + (size_t)(m0 + row) * (KD - K1) + (kc - K1));
      gload_lds16(src, ldsA + buf * 8192 + (it * 256 + w * 64) * 16);
    }
#pragma unroll
    for (int it = 0; it < BN / 64; ++it) {
      int chunk = it * 256 + w * 64 + lane;
      int row = chunk >> 2, c = chunk & 3;
      int kc = k0 + ((c ^ ((row >> 1) & 3)) << 3);
      gload_lds16(Bt + (size_t)(n0 + row) * KD + kc,
                  ldsB + buf * (BN * 64) + (it * 256 + w * 64) * 16);
    }
  };

  f32x4 acc[MR][4] = {};

  stage(0, 0);
  __syncthreads();
  const int NT = KD / 32;
  for (int t = 0; t < NT; ++t) {
    if (t + 1 < NT) stage((t + 1) & 1, t + 1);
    const char* bufA = ldsA + (t & 1) * 8192;
    const char* bufB = ldsB + (t & 1) * (BN * 64);
    s16x8 af[MR], bfr[4];
#pragma unroll
    for (int rt = 0; rt < MR; ++rt) {
      int row = wm * (MR * 16) + rt * 16 + li;
      af[rt] = *(const s16x8*)(bufA + row * 64 + ((g ^ ((row >> 1) & 3)) << 4));
    }
#pragma unroll
    for (int ct = 0; ct < 4; ++ct) {
      int col = wn * 64 + ct * 16 + li;
      bfr[ct] = *(const s16x8*)(bufB + col * 64 + ((g ^ ((col >> 1) & 3)) << 4));
    }
#pragma unroll
    for (int rt = 0; rt < MR; ++rt)
#pragma unroll
      for (int ct = 0; ct < 4; ++ct)
        acc[rt][ct] = mfma16(af[rt], bfr[ct], acc[rt][ct]);
    __syncthreads();
  }

#pragma unroll
  for (int rt = 0; rt < MR; ++rt) {
#pragma unroll
    for (int ct = 0; ct < 4; ++ct) {
      const int growb = m0 + wm * (MR * 16) + rt * 16 + g * 4;   // base row (r=0)
      const int gcol = n0 + wn * 64 + ct * 16 + li;
      if (EPI == 0) {
        const int dir = growb >> 13, b = (growb >> 11) & 3, n = growb & 2047;
        if (gcol < 256) {
          const int h = gcol >> 6, dh = gcol & 63;
#pragma unroll
          for (int r = 0; r < 4; ++r) {
            float q = (acc[rt][ct][r] + bias[gcol]) * SSCALE;
            outb[((size_t)(dir * 16 + b * 4 + h) * 2048 + (n + r)) * 64 + dh] = f2bf(q);
          }
        } else {
          const int c2 = gcol - 256, h = c2 >> 6, dh = c2 & 63;
          u16x4 pk;
#pragma unroll
          for (int r = 0; r < 4; ++r) pk[r] = f2bf(acc[rt][ct][r] + bias2[c2]);
          *(u16x4*)(outb2 + ((size_t)(dir * 16 + b * 4 + h) * 64 + dh) * 2048 + n) = pk;
        }
      } else if (EPI == 1) {
#pragma unroll
        for (int r = 0; r < 4; ++r)
          outb[(size_t)(growb + r) * Ncols + gcol] = f2bf(acc[rt][ct][r] + bias[gcol]);
      } else {
#pragma unroll
        for (int r = 0; r < 4; ++r) {
          int grow = growb + r;
          float x = (grow < 8192) ? res0[(size_t)grow * 256 + gcol]
                                  : res1[(size_t)(grow - 8192) * 256 + gcol];
          outf[(size_t)grow * 256 + gcol] = acc[rt][ct][r] + bias[gcol] + x;
        }
      }
    }
  }
}

// ---------------------------------------------------------------------------
// attention: 32 problems (dir,b,h) x 2 KV-halves x 16 q-tiles of 128.
// 4 waves, 32 q-rows/wave. Transposed-S mfma(K,Q): lane holds 4 consecutive
// keys of one q-row -> packed b64 P-stores + scalar row-sum accumulator.
// Logits tiny (|s|<~1): softmax without max subtraction; partials are
// unnormalized O (f32) + row-sum l, combined by k_combine.
// ---------------------------------------------------------------------------
__global__ __launch_bounds__(256, 3) void k_attn(
    const u16* __restrict__ qk, const u16* __restrict__ vt,
    float* __restrict__ Opart, float* __restrict__ lpart)
{
  __shared__ char Kl[2][8192];
  __shared__ char Vl[2][8192];
  __shared__ char Pl[4][4096];
  const int tid = threadIdx.x, lane = tid & 63, w = tid >> 6;
  const int g = lane >> 4, li = lane & 15;
  const int qblk = blockIdx.x & 15;
  const int half = (blockIdx.x >> 4) & 1;
  const int p = blockIdx.x >> 5;
  const int dir = p & 1;
  const int bh = p >> 1;  // b*4 + h
  const int pidx = dir * 16 + bh;
  const char* Qg = (const char*)qk + (size_t)pidx * 2048 * 128;
  const char* Kg = (const char*)qk + (size_t)((dir ^ 1) * 16 + bh) * 2048 * 128;
  const char* Vg = (const char*)vt + (size_t)((dir ^ 1) * 16 + bh) * 2048 * 128;
  const int q0 = qblk * 128 + w * 32;

  // Q fragments in registers (reused across the whole j loop)
  s16x8 qf[2][2];
#pragma unroll
  for (int qt = 0; qt < 2; ++qt)
#pragma unroll
    for (int ks = 0; ks < 2; ++ks)
      qf[qt][ks] = *(const s16x8*)(Qg + (size_t)(q0 + qt * 16 + li) * 128 + ks * 64 + g * 16);

  auto stageKV = [&](int buf, int jt) {
    const size_t krow0 = (size_t)(half * 1024 + jt * 64);
#pragma unroll
    for (int it = 0; it < 2; ++it) {
      int chunk = it * 256 + w * 64 + lane;
      int row = chunk >> 3, c = chunk & 7;
      int cc = (c ^ (row & 7)) << 4;
      gload_lds16(Kg + (krow0 + row) * 128 + cc, &Kl[buf][(it * 256 + w * 64) * 16]);
    }
#pragma unroll
    for (int it = 0; it < 2; ++it) {
      int chunk = it * 256 + w * 64 + lane;
      int row = chunk >> 3, c = chunk & 7;
      int cc = (c ^ (row & 7)) << 4;
      gload_lds16(Vg + (size_t)row * 4096 + half * 2048 + jt * 128 + cc,
                  &Vl[buf][(it * 256 + w * 64) * 16]);
    }
  };

  f32x4 acco[2][4] = {};
  float accl[2] = {0.f, 0.f};

  stageKV(0, 0);
  __syncthreads();
  for (int jt = 0; jt < 16; ++jt) {
    if (jt + 1 < 16) stageKV((jt + 1) & 1, jt + 1);
    const char* Kb = Kl[jt & 1];
    const char* Vb = Vl[jt & 1];

    // S^T = mfma(K,Q): lane (g,li) holds keys kt*16+g*4+{0..3} of q-row li.
    // exp -> pack bf16 pairs -> one b64 store per (kt,qt), XOR-swizzled.
#pragma unroll
    for (int kt = 0; kt < 4; ++kt) {
      const int krow = kt * 16 + li;
      s16x8 kf0 = *(const s16x8*)(Kb + krow * 128 + ((g ^ (krow & 7)) << 4));
      s16x8 kf1 = *(const s16x8*)(Kb + krow * 128 + (((4 + g) ^ (krow & 7)) << 4));
#pragma unroll
      for (int qt = 0; qt < 2; ++qt) {
        f32x4 s = {0.f, 0.f, 0.f, 0.f};
        s = mfma16(kf0, qf[qt][0], s);
        s = mfma16(kf1, qf[qt][1], s);
        float p0 = __expf(s[0]), p1 = __expf(s[1]);
        float p2 = __expf(s[2]), p3 = __expf(s[3]);
        accl[qt] += (p0 + p1) + (p2 + p3);
        u32x2 pk;
        pk.x = (u32)f2bf(p0) | ((u32)f2bf(p1) << 16);
        pk.y = (u32)f2bf(p2) | ((u32)f2bf(p3) << 16);
        int addr = ((qt * 16 + li) * 128 + kt * 32 + g * 8) ^ ((li & 7) << 4);
        *(u32x2*)(&Pl[w][addr]) = pk;
      }
    }

    // O += P V (same-wave LDS round trip; compiler orders via lgkmcnt)
#pragma unroll
    for (int ks = 0; ks < 2; ++ks) {
      s16x8 vfr[4];
#pragma unroll
      for (int dt = 0; dt < 4; ++dt) {
        const int vrow = dt * 16 + li;
        vfr[dt] = *(const s16x8*)(Vb + vrow * 128 + (((ks * 4 + g) ^ (vrow & 7)) << 4));
      }
#pragma unroll
      for (int qt = 0; qt < 2; ++qt) {
        s16x8 pf = *(const s16x8*)(
            &Pl[w][((qt * 16 + li) * 128 + ks * 64 + g * 16) ^ ((li & 7) << 4)]);
#pragma unroll
        for (int dt = 0; dt < 4; ++dt)
          acco[qt][dt] = mfma16(pf, vfr[dt], acco[qt][dt]);
      }
    }
    __syncthreads();
  }

  // finish row sums (q = li) across the 4 g-groups
#pragma unroll
  for (int qt = 0; qt < 2; ++qt) {
    float v = accl[qt];
    v += __shfl_xor(v, 16);
    v += __shfl_xor(v, 32);
    accl[qt] = v;
  }

  const int b = bh >> 2, h = bh & 3;
  const size_t rowbase = (size_t)dir * 8192 + (size_t)b * 2048 + q0;
  float* Oh = Opart + (size_t)half * 4194304;
#pragma unroll
  for (int qt = 0; qt < 2; ++qt)
#pragma unroll
    for (int dt = 0; dt < 4; ++dt)
#pragma unroll
      for (int r = 0; r < 4; ++r)
        Oh[(rowbase + qt * 16 + g * 4 + r) * 256 + h * 64 + dt * 16 + li] = acco[qt][dt][r];
  if (lane < 16) {
#pragma unroll
    for (int qt = 0; qt < 2; ++qt)
      lpart[half * 65536 + pidx * 2048 + q0 + qt * 16 + li] = accl[qt];
  }
}

// ---------------------------------------------------------------------------
// combine: m_all = bf16((O0+O1) / (l0+l1))
// ---------------------------------------------------------------------------
__global__ __launch_bounds__(256) void k_combine(
    const float* __restrict__ Op, const float* __restrict__ lp,
    u16* __restrict__ m_all)
{
  int t = blockIdx.x * 256 + threadIdx.x;  // 16384*64 threads, 4 f32 each
  int row = t >> 6, quad = t & 63;
  int dh0 = quad * 4;
  int dir = row >> 13, b = (row >> 11) & 3, n = row & 2047, h = dh0 >> 6;
  int pidx = dir * 16 + b * 4 + h;
  float l = lp[pidx * 2048 + n] + lp[65536 + pidx * 2048 + n];
  float invl = 1.0f / l;
  f32x4 o0 = *(const f32x4*)(Op + (size_t)row * 256 + dh0);
  f32x4 o1 = *(const f32x4*)(Op + 4194304 + (size_t)row * 256 + dh0);
  u16x4 r4;
#pragma unroll
  for (int j = 0; j < 4; ++j) r4[j] = f2bf((o0[j] + o1[j]) * invl);
  *(u16x4*)(m_all + (size_t)row * 256 + dh0) = r4;
}

// ---------------------------------------------------------------------------
// layernorm (over 512) + exact gelu; one wave per row
// ---------------------------------------------------------------------------
__global__ __launch_bounds__(256) void k_ln_gelu(
    const u16* __restrict__ h, const float* __restrict__ lg,
    const float* __restrict__ lb, u16* __restrict__ o)
{
  int lane = threadIdx.x & 63;
  size_t row = blockIdx.x * 4 + (threadIdx.x >> 6);
  s16x8 v = *(const s16x8*)(h + row * 512 + lane * 8);
  float f[8], s = 0.f, s2 = 0.f;
#pragma unroll
  for (int j = 0; j < 8; ++j) { f[j] = bf2f((u16)v[j]); s += f[j]; s2 += f[j] * f[j]; }
#pragma unroll
  for (int m = 1; m < 64; m <<= 1) { s += __shfl_xor(s, m); s2 += __shfl_xor(s2, m); }
  float mu = s * (1.0f / 512.0f);
  float var = s2 * (1.0f / 512.0f) - mu * mu;
  float rs = rsqrtf(var + 1e-5f);
  s16x8 ov;
#pragma unroll
  for (int j = 0; j < 8; ++j) {
    int c = lane * 8 + j;
    float y = (f[j] - mu) * rs * lg[c] + lb[c];
    float ge = 0.5f * y * (1.0f + erff(y * 0.70710678118654752f));
    ov[j] = (short)f2bf(ge);
  }
  *(s16x8*)(o + row * 512 + lane * 8) = ov;
}

// ---------------------------------------------------------------------------
extern "C" void kernel_launch(void* const* d_in, const int* in_sizes, int n_in,
                              void* d_out, int out_size, void* d_ws, size_t ws_size,
                              hipStream_t stream)
{
  const float* x0  = (const float*)d_in[0];
  const float* x1  = (const float*)d_in[1];
  const float* Wqk = (const float*)d_in[2];
  const float* bqk = (const float*)d_in[3];
  const float* Wv  = (const float*)d_in[4];
  const float* bv  = (const float*)d_in[5];
  const float* Wo  = (const float*)d_in[6];
  const float* bo  = (const float*)d_in[7];
  const float* W1  = (const float*)d_in[8];
  const float* b1  = (const float*)d_in[9];
  const float* lg  = (const float*)d_in[10];
  const float* lb  = (const float*)d_in[11];
  const float* W2  = (const float*)d_in[12];
  const float* b2  = (const float*)d_in[13];
  float* out = (float*)d_out;
  char* ws = (char*)d_ws;

  u16*   Xb    = (u16*)(ws + 0);          // 16384x256 bf16
  u16*   qk    = (u16*)(ws + 8388608);    // [2][4][4][2048][64] bf16 (scaled)
  u16*   vt    = (u16*)(ws + 16777216);   // [2][4][4][64][2048] bf16 (V^T)
  u16*   m_all = (u16*)(ws + 25165824);   // 16384x256 bf16
  float* lpart = (float*)(ws + 33554432); // [2][32][2048] f32
  u16*   mo    = (u16*)(ws + 34078720);   // 16384x256 bf16
  float* Opart = (float*)(ws + 42467328); // [2][16384][256] f32 (dead after combine)
  u16*   hpre  = (u16*)(ws + 42467328);   // 16384x512 bf16 (overlays Opart)
  u16*   gact  = (u16*)(ws + 59244544);   // 16384x512 bf16 (overlays Opart)
  u16*   btqkv = (u16*)(ws + 76021760);   // [512][256]
  u16*   bto   = (u16*)(ws + 76283904);   // [256][256]
  u16*   bt1   = (u16*)(ws + 76414976);   // [512][512]
  u16*   bt2   = (u16*)(ws + 76939264);   // [256][512]

  k_prep<<<dim3(18688), dim3(256), 0, stream>>>(x0, x1, Wqk, Wv, Wo, W1, W2,
                                                btqkv, bto, bt1, bt2, Xb);
  k_gemm<256, 256, 0, 128><<<dim3(128, 4), dim3(256), 0, stream>>>(
      Xb, nullptr, btqkv, bqk, bv, nullptr, nullptr, qk, vt, nullptr, 512);
  k_attn<<<dim3(1024), dim3(256), 0, stream>>>(qk, vt, Opart, lpart);
  k_combine<<<dim3(4096), dim3(256), 0, stream>>>(Opart, lpart, m_all);
  k_gemm<256, 256, 1, 64><<<dim3(128, 4), dim3(256), 0, stream>>>(
      m_all, nullptr, bto, bo, nullptr, nullptr, nullptr, mo, nullptr, nullptr, 256);
  k_gemm<512, 256, 1, 128><<<dim3(128, 4), dim3(256), 0, stream>>>(
      Xb, mo, bt1, b1, nullptr, nullptr, nullptr, hpre, nullptr, nullptr, 512);
  k_ln_gelu<<<dim3(4096), dim3(256), 0, stream>>>(hpre, lg, lb, gact);
  k_gemm<512, 512, 3, 64><<<dim3(128, 4), dim3(256), 0, stream>>>(
      gact, nullptr, bt2, b2, nullptr, x0, x1, nullptr, nullptr, out, 256);
}